// Round 1
// baseline (25.572 us; speedup 1.0000x reference)
//
#include <hip/hip_runtime.h>

// LengthRegulator: inputs [B, T_IN, D] f32, durations [B, T_IN] f32.
// reps = floor(dur + 0.5); out[b, m, :] = inputs[b, t, :] where
// cumsum[b][t] <= m < cumsum[b][t+1]; zeros for m >= output_lens[b].
// d_out = out flat [B*max_len*D] ++ output_lens [B] (written as float).

#define BATCH 16
#define T_IN 512
#define DIM 384
#define D4 (DIM / 4)  // 96 float4 per row

// One block per batch: compute reps, exclusive prefix sum -> d_ws cumsum,
// and output_lens (as float) into the tail of d_out.
__global__ void lr_scan_kernel(const float* __restrict__ dur,
                               int* __restrict__ cum,
                               float* __restrict__ lens_out) {
    __shared__ int s[T_IN];
    const int b = blockIdx.x;
    const int t = threadIdx.x;

    float d = dur[b * T_IN + t];
    int rep = (int)floorf(d + 0.5f);
    s[t] = rep;
    __syncthreads();

    // Hillis-Steele inclusive scan over 512 elements (9 steps).
    #pragma unroll
    for (int off = 1; off < T_IN; off <<= 1) {
        int v = (t >= off) ? s[t - off] : 0;
        __syncthreads();
        s[t] += v;
        __syncthreads();
    }

    // Exclusive cumsum with leading zero: cum[b][0]=0, cum[b][t+1]=incl[t].
    int* c = cum + b * (T_IN + 1);
    if (t == 0) c[0] = 0;
    c[t + 1] = s[t];
    if (t == T_IN - 1) lens_out[b] = (float)s[t];
}

// grid.y = batch. Grid-stride over max_len*D4 float4 vectors of that batch.
__global__ void lr_gather_kernel(const float4* __restrict__ in4,
                                 const int* __restrict__ cum,
                                 float4* __restrict__ out4,
                                 int max_len) {
    __shared__ int c[T_IN + 1];
    const int b = blockIdx.y;

    // Stage this batch's cumsum into LDS.
    for (int i = threadIdx.x; i < T_IN + 1; i += blockDim.x)
        c[i] = cum[b * (T_IN + 1) + i];
    __syncthreads();

    const int len = c[T_IN];
    const int per_b = max_len * D4;
    const int stride = gridDim.x * blockDim.x;
    const float4* src_b = in4 + (size_t)b * T_IN * D4;
    float4* dst_b = out4 + (size_t)b * per_b;

    for (int v = blockIdx.x * blockDim.x + threadIdx.x; v < per_b; v += stride) {
        int m = v / D4;       // constant divisor 96 -> magic mul
        int d4 = v - m * D4;
        float4 val = make_float4(0.f, 0.f, 0.f, 0.f);
        if (m < len) {
            // find t: c[t] <= m < c[t+1]; c[0]=0 <= m always.
            int lo = 0, hi = T_IN;
            while (hi - lo > 1) {
                int mid = (lo + hi) >> 1;
                if (c[mid] <= m) lo = mid; else hi = mid;
            }
            val = src_b[lo * D4 + d4];
        }
        dst_b[v] = val;
    }
}

extern "C" void kernel_launch(void* const* d_in, const int* in_sizes, int n_in,
                              void* d_out, int out_size, void* d_ws, size_t ws_size,
                              hipStream_t stream) {
    const float* inputs = (const float*)d_in[0];
    const float* durations = (const float*)d_in[1];
    float* out = (float*)d_out;

    const int max_len = (out_size - BATCH) / (BATCH * DIM);
    int* cum = (int*)d_ws;                                  // B*(T_IN+1) ints
    float* lens_out = out + (size_t)BATCH * max_len * DIM;  // tail of d_out

    lr_scan_kernel<<<BATCH, T_IN, 0, stream>>>(durations, cum, lens_out);

    const int per_b = max_len * D4;                 // float4 vectors per batch
    const int block = 256;
    int gx = (per_b + block - 1) / block;
    if (gx > 128) gx = 128;                         // 128 * 16 = 2048 blocks total
    dim3 grid(gx, BATCH);
    lr_gather_kernel<<<grid, block, 0, stream>>>((const float4*)inputs, cum,
                                                 (float4*)out, max_len);
}

// Round 2
// 23.203 us; speedup vs baseline: 1.1021x; 1.1021x over previous
//
#include <hip/hip_runtime.h>

// LengthRegulator: inputs [B, T_IN, D] f32, durations [B, T_IN] f32.
// reps = floor(dur + 0.5); out[b, m, :] = inputs[b, t, :] where
// cumsum[b][t] <= m < cumsum[b][t+1]; zeros for m >= output_lens[b].
// d_out = out flat [B*max_len*D] ++ output_lens [B] (written as float).
//
// Strategy: kernel A scans durations per batch and materializes an explicit
// frame->token map (int, -1 = zero-fill) in d_ws. Kernel B is a pure
// streaming gather: one map load + one float4 load + one float4 store.

#define BATCH 16
#define T_IN 512
#define DIM 384
#define D4 (DIM / 4)  // 96 float4 per row

// One block (512 threads) per batch: reps, inclusive scan, output_lens,
// and scatter token index into map[b][cum[t] .. cum[t+1]).
__global__ void lr_scan_map_kernel(const float* __restrict__ dur,
                                   int* __restrict__ map,
                                   float* __restrict__ lens_out,
                                   int max_len) {
    __shared__ int s[T_IN];
    __shared__ int len_s;
    const int b = blockIdx.x;
    const int t = threadIdx.x;

    float d = dur[b * T_IN + t];
    int rep = (int)floorf(d + 0.5f);
    s[t] = rep;
    __syncthreads();

    // Hillis-Steele inclusive scan over 512 elements (9 steps).
    #pragma unroll
    for (int off = 1; off < T_IN; off <<= 1) {
        int v = (t >= off) ? s[t - off] : 0;
        __syncthreads();
        s[t] += v;
        __syncthreads();
    }

    if (t == T_IN - 1) {
        len_s = s[t];
        lens_out[b] = (float)s[t];
    }
    __syncthreads();

    int* mp = map + (size_t)b * max_len;
    // Scatter: frames [incl - rep, incl) belong to token t.
    const int end = s[t];
    for (int m = end - rep; m < end; ++m) mp[m] = t;
    // Tail: frames beyond this batch's length are zero-fill.
    const int len = len_s;
    for (int m = len + t; m < max_len; m += T_IN) mp[m] = -1;
}

// grid.y = batch. Grid-stride over max_len*D4 float4 vectors of that batch.
__global__ void lr_gather_kernel(const float4* __restrict__ in4,
                                 const int* __restrict__ map,
                                 float4* __restrict__ out4,
                                 int max_len) {
    const int b = blockIdx.y;
    const int per_b = max_len * D4;
    const int stride = gridDim.x * blockDim.x;
    const int* mp = map + (size_t)b * max_len;
    const float4* src_b = in4 + (size_t)b * T_IN * D4;
    float4* dst_b = out4 + (size_t)b * per_b;

    for (int v = blockIdx.x * blockDim.x + threadIdx.x; v < per_b; v += stride) {
        int m = v / D4;          // constant divisor 96 -> magic mul
        int d4 = v - m * D4;
        int t = mp[m];           // broadcast within wave (<=2 distinct m), L2-hot
        float4 val = make_float4(0.f, 0.f, 0.f, 0.f);
        if (t >= 0) val = src_b[t * D4 + d4];
        dst_b[v] = val;
    }
}

extern "C" void kernel_launch(void* const* d_in, const int* in_sizes, int n_in,
                              void* d_out, int out_size, void* d_ws, size_t ws_size,
                              hipStream_t stream) {
    const float* inputs = (const float*)d_in[0];
    const float* durations = (const float*)d_in[1];
    float* out = (float*)d_out;

    const int max_len = (out_size - BATCH) / (BATCH * DIM);
    int* map = (int*)d_ws;                                  // B * max_len ints
    float* lens_out = out + (size_t)BATCH * max_len * DIM;  // tail of d_out

    lr_scan_map_kernel<<<BATCH, T_IN, 0, stream>>>(durations, map, lens_out,
                                                   max_len);

    const int per_b = max_len * D4;                 // float4 vectors per batch
    const int block = 256;
    int gx = (per_b + block - 1) / block;
    if (gx > 128) gx = 128;                         // 128 * 16 = 2048 blocks total
    dim3 grid(gx, BATCH);
    lr_gather_kernel<<<grid, block, 0, stream>>>((const float4*)inputs, map,
                                                 (float4*)out, max_len);
}

// Round 3
// 16.938 us; speedup vs baseline: 1.5097x; 1.3699x over previous
//
#include <hip/hip_runtime.h>

// LengthRegulator fused single-kernel:
// reps = floor(dur + 0.5); out[b, m, :] = inputs[b, t, :] where
// cumsum[b][t] <= m < cumsum[b][t+1]; zeros for m >= output_lens[b].
// d_out = out flat [B*max_len*D] ++ output_lens [B] (as float).
//
// Each block: one batch (blockIdx.y) x 24 contiguous output frames
// (blockIdx.x). Redundant per-block shfl-scan of the 512 durations
// (registers only, 2 barriers), scatter token ids into a 24-entry LDS
// frame->token map, then a pure streaming float4 gather.

#define BATCH 16
#define T_IN 512
#define DIM 384
#define D4 96            // float4 per row
#define FPB 24           // output frames per block
#define VPB (FPB * D4)   // 2304 float4 vectors per block
#define NT 256           // threads per block (4 waves)

__global__ __launch_bounds__(NT) void lr_fused_kernel(
    const float* __restrict__ dur,
    const float4* __restrict__ in4,
    float4* __restrict__ out4,
    float* __restrict__ lens_out,
    int max_len) {
    __shared__ int wsum[NT / 64];
    __shared__ int smap[FPB];

    const int b = blockIdx.y;
    const int tid = threadIdx.x;
    const int lane = tid & 63;
    const int w = tid >> 6;

    // ---- scan: 512 reps, 2 per thread, all in registers ----
    float2 dp = *(const float2*)(dur + b * T_IN + 2 * tid);
    int r0 = (int)floorf(dp.x + 0.5f);
    int r1 = (int)floorf(dp.y + 0.5f);
    int s = r0 + r1;
    int incl = s;
    #pragma unroll
    for (int off = 1; off < 64; off <<= 1) {
        int v = __shfl_up(incl, off);
        if (lane >= off) incl += v;
    }
    if (lane == 63) wsum[w] = incl;
    if (tid < FPB) smap[tid] = -1;   // default: zero-fill frame
    __syncthreads();

    int waveoff = 0;
    #pragma unroll
    for (int i = 0; i < NT / 64; ++i)
        if (i < w) waveoff += wsum[i];

    const int c0 = waveoff + incl - s;  // cumsum before token 2*tid
    const int c1 = c0 + r0;             // before token 2*tid+1
    const int c2 = c0 + s;              // before token 2*tid+2

    const int f0 = blockIdx.x * FPB;
    const int f1 = f0 + FPB;
    // scatter: token 2*tid covers frames [c0, c1), token 2*tid+1 [c1, c2)
    {
        int lo = max(c0, f0), hi = min(c1, f1);
        for (int j = lo; j < hi; ++j) smap[j - f0] = 2 * tid;
        lo = max(c1, f0); hi = min(c2, f1);
        for (int j = lo; j < hi; ++j) smap[j - f0] = 2 * tid + 1;
    }
    if (blockIdx.x == 0 && tid == NT - 1) lens_out[b] = (float)c2;
    __syncthreads();

    // ---- gather: 24 frames = 2304 float4, 9 per thread ----
    const int per_b = max_len * D4;
    const int v0 = blockIdx.x * VPB;
    const float4* src_b = in4 + (size_t)b * T_IN * D4;
    float4* dst_b = out4 + (size_t)b * per_b;

    #pragma unroll
    for (int k = 0; k < VPB / NT; ++k) {
        int lv = tid + k * NT;          // 0..2303 within block chunk
        int v = v0 + lv;
        if (v >= per_b) break;
        int ml = lv / D4;               // local frame 0..23 (const divisor)
        int d4 = lv - ml * D4;
        int t = smap[ml];
        float4 val = make_float4(0.f, 0.f, 0.f, 0.f);
        if (t >= 0) val = src_b[t * D4 + d4];
        dst_b[v] = val;
    }
}

extern "C" void kernel_launch(void* const* d_in, const int* in_sizes, int n_in,
                              void* d_out, int out_size, void* d_ws, size_t ws_size,
                              hipStream_t stream) {
    const float* inputs = (const float*)d_in[0];
    const float* durations = (const float*)d_in[1];
    float* out = (float*)d_out;

    const int max_len = (out_size - BATCH) / (BATCH * DIM);
    float* lens_out = out + (size_t)BATCH * max_len * DIM;

    const int gx = (max_len + FPB - 1) / FPB;
    dim3 grid(gx, BATCH);
    lr_fused_kernel<<<grid, NT, 0, stream>>>(durations, (const float4*)inputs,
                                             (float4*)out, lens_out, max_len);
}

// Round 5
// 16.287 us; speedup vs baseline: 1.5701x; 1.0400x over previous
//
#include <hip/hip_runtime.h>

// LengthRegulator fused single-kernel:
// reps = floor(dur + 0.5); out[b, m, :] = inputs[b, t, :] where
// cumsum[b][t] <= m < cumsum[b][t+1]; zeros for m >= output_lens[b].
// d_out = out flat [B*max_len*D] ++ output_lens [B] (as float).
//
// Each block: one batch x 24 contiguous output frames. Redundant per-block
// register shfl-scan of the 512 durations (2 barriers), scatter token ids
// into a 24-entry LDS frame->token map, then streaming float4 gather.
// XCD-chunked blockIdx swizzle keeps adjacent frames (which reuse the same
// input rows) on the same XCD's L2; non-temporal output stores keep those
// rows from being evicted by the 52 MB write stream.

#define BATCH 16
#define T_IN 512
#define DIM 384
#define D4 96            // float4 per row
#define FPB 24           // output frames per block
#define VPB (FPB * D4)   // 2304 float4 vectors per block
#define NT 256           // threads per block (4 waves)

typedef float floatx4 __attribute__((ext_vector_type(4)));  // native vec for nt-store

__global__ __launch_bounds__(NT) void lr_fused_kernel(
    const float* __restrict__ dur,
    const floatx4* __restrict__ in4,
    floatx4* __restrict__ out4,
    float* __restrict__ lens_out,
    int max_len, int gx) {
    __shared__ int wsum[NT / 64];
    __shared__ int smap[FPB];

    // XCD-chunked swizzle: HW round-robins dispatch id % 8 across XCDs, so
    // give XCD k the contiguous work range [k*nwg/8, (k+1)*nwg/8).
    const int nwg = gridDim.x;               // 16 * gx, divisible by 8
    const int id = blockIdx.x;
    const int wid = (id & 7) * (nwg >> 3) + (id >> 3);
    const int b = wid / gx;                  // batch
    const int fx = wid - b * gx;             // frame-chunk within batch

    const int tid = threadIdx.x;
    const int lane = tid & 63;
    const int w = tid >> 6;

    // ---- scan: 512 reps, 2 per thread, registers only ----
    float2 dp = *(const float2*)(dur + b * T_IN + 2 * tid);
    int r0 = (int)floorf(dp.x + 0.5f);
    int r1 = (int)floorf(dp.y + 0.5f);
    int s = r0 + r1;
    int incl = s;
    #pragma unroll
    for (int off = 1; off < 64; off <<= 1) {
        int v = __shfl_up(incl, off);
        if (lane >= off) incl += v;
    }
    if (lane == 63) wsum[w] = incl;
    if (tid < FPB) smap[tid] = -1;   // default: zero-fill frame
    __syncthreads();

    int waveoff = 0;
    #pragma unroll
    for (int i = 0; i < NT / 64; ++i)
        if (i < w) waveoff += wsum[i];

    const int c0 = waveoff + incl - s;  // cumsum before token 2*tid
    const int c1 = c0 + r0;             // before token 2*tid+1
    const int c2 = c0 + s;              // before token 2*tid+2

    const int f0 = fx * FPB;
    const int f1 = f0 + FPB;
    // scatter: token 2*tid covers frames [c0, c1), token 2*tid+1 [c1, c2)
    {
        int lo = max(c0, f0), hi = min(c1, f1);
        for (int j = lo; j < hi; ++j) smap[j - f0] = 2 * tid;
        lo = max(c1, f0); hi = min(c2, f1);
        for (int j = lo; j < hi; ++j) smap[j - f0] = 2 * tid + 1;
    }
    if (fx == 0 && tid == NT - 1) lens_out[b] = (float)c2;
    __syncthreads();

    // ---- gather: 24 frames = 2304 float4, 9 per thread ----
    const int per_b = max_len * D4;
    const int v0 = fx * VPB;
    const floatx4* src_b = in4 + (size_t)b * T_IN * D4;
    floatx4* dst_b = out4 + (size_t)b * per_b;

    #pragma unroll
    for (int k = 0; k < VPB / NT; ++k) {
        int lv = tid + k * NT;          // 0..2303 within block chunk
        int v = v0 + lv;
        if (v >= per_b) break;
        int ml = lv / D4;               // local frame 0..23 (const divisor)
        int d4 = lv - ml * D4;
        int t = smap[ml];
        floatx4 val = (floatx4)(0.f);
        if (t >= 0) val = src_b[t * D4 + d4];
        __builtin_nontemporal_store(val, &dst_b[v]);
    }
}

extern "C" void kernel_launch(void* const* d_in, const int* in_sizes, int n_in,
                              void* d_out, int out_size, void* d_ws, size_t ws_size,
                              hipStream_t stream) {
    const float* inputs = (const float*)d_in[0];
    const float* durations = (const float*)d_in[1];
    float* out = (float*)d_out;

    const int max_len = (out_size - BATCH) / (BATCH * DIM);
    float* lens_out = out + (size_t)BATCH * max_len * DIM;

    const int gx = (max_len + FPB - 1) / FPB;
    dim3 grid(gx * BATCH);
    lr_fused_kernel<<<grid, NT, 0, stream>>>(durations, (const floatx4*)inputs,
                                             (floatx4*)out, lens_out, max_len,
                                             gx);
}